// Round 6
// baseline (1213.122 us; speedup 1.0000x reference)
//
#include <hip/hip_runtime.h>
#include <stdint.h>

// Problem constants (reference: B,S,D,H = 2,2048,2048,16; DH=128)
constexpr int kBz = 2;
constexpr int kSz = 2048;
constexpr int kDz = 2048;
constexpr int kHz = 16;
constexpr int kDH = 128;
constexpr int kMz = kBz * kSz;  // 4096 rows of x

typedef __attribute__((ext_vector_type(8)))  short bf16x8;
typedef __attribute__((ext_vector_type(16))) float f32x16;

__device__ __forceinline__ ushort f2bf_rne(float f) {
    const uint u = __float_as_uint(f);
    return (ushort)((u + 0x7FFFu + ((u >> 16) & 1u)) >> 16);
}
__device__ __forceinline__ ushort f2bf_hi(float f) {
    return (ushort)(__float_as_uint(f) >> 16);
}
__device__ __forceinline__ float bf2f(ushort h) {
    return __uint_as_float(((uint)h) << 16);
}
// pack 2 f32 -> 1 u32 of 2 RNE bf16 (low = a, high = b)
__device__ __forceinline__ uint cvt_pk_bf16(float a, float b) {
    uint r;
    asm("v_cvt_pk_bf16_f32 %0, %1, %2" : "=v"(r) : "v"(a), "v"(b));
    return r;
}
// split fp32 -> (hi = truncated bf16, lo = rne bf16 of residual); packed pairs
__device__ __forceinline__ void cvt_split(const float4 v, uint2& hi, uint2& lo) {
    const ushort h0 = f2bf_hi(v.x);
    const ushort h1 = f2bf_hi(v.y);
    const ushort h2 = f2bf_hi(v.z);
    const ushort h3 = f2bf_hi(v.w);
    const ushort l0 = f2bf_rne(v.x - bf2f(h0));
    const ushort l1 = f2bf_rne(v.y - bf2f(h1));
    const ushort l2 = f2bf_rne(v.z - bf2f(h2));
    const ushort l3 = f2bf_rne(v.w - bf2f(h3));
    hi.x = (uint)h0 | ((uint)h1 << 16);
    hi.y = (uint)h2 | ((uint)h3 << 16);
    lo.x = (uint)l0 | ((uint)l1 << 16);
    lo.y = (uint)l2 | ((uint)l3 << 16);
}
// assemble a bf16x8 A-fragment from two 8B (4-element) loads
__device__ __forceinline__ bf16x8 ld2x8(const ushort* p0, const ushort* p1) {
    const ushort4 a = *(const ushort4*)p0;
    const ushort4 b = *(const ushort4*)p1;
    bf16x8 r;
    r[0] = (short)a.x; r[1] = (short)a.y; r[2] = (short)a.z; r[3] = (short)a.w;
    r[4] = (short)b.x; r[5] = (short)b.y; r[6] = (short)b.z; r[7] = (short)b.w;
    return r;
}

// ---------------------------------------------------------------------------
// Kernel W: split Wo (fp32, H x DH x DH) into bf16 hi/lo planes.
// ---------------------------------------------------------------------------
__global__ __launch_bounds__(256)
void wo_split_kernel(const float* __restrict__ Wo,
                     ushort* __restrict__ Wohi, ushort* __restrict__ Wolo)
{
    const int i = (blockIdx.x * 256 + threadIdx.x) * 4;
    const float4 v = *(const float4*)&Wo[i];
    uint2 ph, pl;
    cvt_split(v, ph, pl);
    *(uint2*)&Wohi[i] = ph;
    *(uint2*)&Wolo[i] = pl;
}

// ---------------------------------------------------------------------------
// Kernel A: fused QKV projection via split-bf16 MFMA (validated round 4/5).
// Q,K stored as split bf16 hi/lo planes in (B,H,S,DH); V stored split AND
// TRANSPOSED: Vt[(b,h),d,s] hi/lo (feeds PV MFMA A-operand directly).
// ---------------------------------------------------------------------------
__global__ __launch_bounds__(256)
void qkv_proj_kernel(const float* __restrict__ x,
                     const float* __restrict__ Wq, const float* __restrict__ Wk,
                     const float* __restrict__ Wv,
                     const float* __restrict__ bq, const float* __restrict__ bk,
                     const float* __restrict__ bv,
                     ushort* __restrict__ Qhi, ushort* __restrict__ Qlo,
                     ushort* __restrict__ Khi, ushort* __restrict__ Klo,
                     ushort* __restrict__ Vthi, ushort* __restrict__ Vtlo)
{
    const int z = blockIdx.z;
    const float* W    = (z == 0) ? Wq : (z == 1) ? Wk : Wv;
    const float* bias = (z == 0) ? bq : (z == 1) ? bk : bv;

    __shared__ ushort AsHi[4 * 1032];
    __shared__ ushort AsLo[4 * 1032];
    __shared__ ushort BsHi[4 * 1032];
    __shared__ ushort BsLo[4 * 1032];

    const int tid  = threadIdx.x;
    const int lane = tid & 63;
    const int wid  = tid >> 6;
    const int wr   = (wid >> 1) * 64;
    const int wc   = (wid & 1) * 64;
    const int row0 = blockIdx.y * 128;
    const int col0 = blockIdx.x * 128;

    f32x16 acc[2][2];
#pragma unroll
    for (int fi = 0; fi < 2; ++fi)
#pragma unroll
        for (int fj = 0; fj < 2; ++fj)
#pragma unroll
            for (int e = 0; e < 16; ++e) acc[fi][fj][e] = 0.0f;

    for (int kt = 0; kt < kDz; kt += 32) {
#pragma unroll
        for (int t = 0; t < 4; ++t) {
            const int idx = tid + t * 256;
            const int m   = idx >> 3;
            const int q   = idx & 7;
            const int off = (q >> 1) * 1032 + m * 8 + (q & 1) * 4;
            {
                const float4 av = *(const float4*)&x[(size_t)(row0 + m) * kDz + kt + q * 4];
                uint2 ph, pl;
                cvt_split(av, ph, pl);
                *(uint2*)&AsHi[off] = ph;
                *(uint2*)&AsLo[off] = pl;
            }
            {
                const float4 wv4 = *(const float4*)&W[(size_t)(col0 + m) * kDz + kt + q * 4];
                uint2 ph, pl;
                cvt_split(wv4, ph, pl);
                *(uint2*)&BsHi[off] = ph;
                *(uint2*)&BsLo[off] = pl;
            }
        }
        __syncthreads();

#pragma unroll
        for (int ks = 0; ks < 2; ++ks) {
            const int base = (ks * 2 + (lane >> 5)) * 1032;
            bf16x8 ah[2], al[2], bh[2], bl[2];
#pragma unroll
            for (int f = 0; f < 2; ++f) {
                const int ma = (wr + f * 32 + (lane & 31)) * 8;
                ah[f] = *(const bf16x8*)&AsHi[base + ma];
                al[f] = *(const bf16x8*)&AsLo[base + ma];
                const int nb = (wc + f * 32 + (lane & 31)) * 8;
                bh[f] = *(const bf16x8*)&BsHi[base + nb];
                bl[f] = *(const bf16x8*)&BsLo[base + nb];
            }
#pragma unroll
            for (int fi = 0; fi < 2; ++fi)
#pragma unroll
                for (int fj = 0; fj < 2; ++fj) {
                    acc[fi][fj] = __builtin_amdgcn_mfma_f32_32x32x16_bf16(
                        ah[fi], bh[fj], acc[fi][fj], 0, 0, 0);
                    acc[fi][fj] = __builtin_amdgcn_mfma_f32_32x32x16_bf16(
                        ah[fi], bl[fj], acc[fi][fj], 0, 0, 0);
                    acc[fi][fj] = __builtin_amdgcn_mfma_f32_32x32x16_bf16(
                        al[fi], bh[fj], acc[fi][fj], 0, 0, 0);
                }
        }
        __syncthreads();
    }

    const int head = blockIdx.x;
    if (z < 2) {
        ushort* HiP = (z == 0) ? Qhi : Khi;
        ushort* LoP = (z == 0) ? Qlo : Klo;
#pragma unroll
        for (int fj = 0; fj < 2; ++fj) {
            const int dh  = wc + fj * 32 + (lane & 31);
            const float bvs = bias[head * kDH + dh];
#pragma unroll
            for (int fi = 0; fi < 2; ++fi) {
                const int rb = row0 + wr + fi * 32 + ((lane >> 5) << 2);
#pragma unroll
                for (int g = 0; g < 4; ++g)
#pragma unroll
                    for (int e = 0; e < 4; ++e) {
                        const int row = rb + g * 8 + e;
                        const int bb  = row >> 11;
                        const int ss  = row & (kSz - 1);
                        const size_t idx =
                            ((size_t)(bb * kHz + head) * kSz + ss) * kDH + dh;
                        const float val = acc[fi][fj][g * 4 + e] + bvs;
                        const ushort hb = f2bf_hi(val);
                        HiP[idx] = hb;
                        LoP[idx] = f2bf_rne(val - bf2f(hb));
                    }
            }
        }
    } else {
#pragma unroll
        for (int fj = 0; fj < 2; ++fj) {
            const int dh  = wc + fj * 32 + (lane & 31);
            const float bvs = bias[head * kDH + dh];
#pragma unroll
            for (int fi = 0; fi < 2; ++fi) {
                const int rb = row0 + wr + fi * 32 + ((lane >> 5) << 2);
#pragma unroll
                for (int g = 0; g < 4; ++g) {
                    const int srow = rb + g * 8;
                    const int bb   = srow >> 11;
                    const int ss   = srow & (kSz - 1);
                    ushort4 h4, l4;
                    {
                        const float v0 = acc[fi][fj][g * 4 + 0] + bvs;
                        const float v1 = acc[fi][fj][g * 4 + 1] + bvs;
                        const float v2 = acc[fi][fj][g * 4 + 2] + bvs;
                        const float v3 = acc[fi][fj][g * 4 + 3] + bvs;
                        h4.x = f2bf_hi(v0); l4.x = f2bf_rne(v0 - bf2f(h4.x));
                        h4.y = f2bf_hi(v1); l4.y = f2bf_rne(v1 - bf2f(h4.y));
                        h4.z = f2bf_hi(v2); l4.z = f2bf_rne(v2 - bf2f(h4.z));
                        h4.w = f2bf_hi(v3); l4.w = f2bf_rne(v3 - bf2f(h4.w));
                    }
                    const size_t base =
                        ((size_t)((bb * kHz + head) * kDH + dh)) * kSz + ss;
                    *(ushort4*)&Vthi[base] = h4;
                    *(ushort4*)&Vtlo[base] = l4;
                }
            }
        }
    }
}

// ---------------------------------------------------------------------------
// Kernel B: barrier-free all-MFMA flash attention + fused out-projection.
// Block = 128 thr = 2 fully-independent waves; each wave owns 32 queries and
// iterates all KV tiles (KVB=32).  NO LDS, NO __syncthreads anywhere.
//
// QK^T: D = K·Q^T (A=K frags 16B direct global, B=Q frags in regs, 3-term
// split, 2 acc chains).  D: col=lane&31=query i, row j=(r&3)+8(r>>2)+4half
// (HW-validated rounds 4/5).  Softmax in-register per query pair
// (shfl_xor(32) merge), mask applied MULTIPLICATIVELY post-exp (algebraically
// identical), T13 defer-max THR=8 (wave-uniform __all).
//
// P handoff WITHOUT any layout shuffle: P packed to bf16 in natural register
// order; PV loads V with the matching j-PERMUTED addresses (two 8B loads per
// fragment) — Σ_j V[d][j]P[j][i] is invariant under a shared j-permutation.
// Same trick for the out-projection (O in reg order, Wo d-permuted loads).
// ---------------------------------------------------------------------------
__global__ __launch_bounds__(128, 2)
void attn_fused_kernel(const ushort* __restrict__ Qhi, const ushort* __restrict__ Qlo,
                       const ushort* __restrict__ Khi, const ushort* __restrict__ Klo,
                       const ushort* __restrict__ Vthi, const ushort* __restrict__ Vtlo,
                       const uint8_t* __restrict__ mask,
                       const ushort* __restrict__ Wohi, const ushort* __restrict__ Wolo,
                       const float* __restrict__ bo, float* __restrict__ out)
{
    const int tid  = threadIdx.x;
    const int lane = tid & 63;
    const int wid  = tid >> 6;       // 0..1: which 32-query group
    const int half = lane >> 5;
    const int l31  = lane & 31;

    // XCD-aware swizzle (validated): 1024 blocks = 8 XCDs x 128
    const int nb = (blockIdx.x & 7) * 128 + (blockIdx.x >> 3);
    const int bh = nb >> 5;
    const int qb = nb & 31;
    const int bb = bh >> 4;
    const int h  = bh & 15;
    const int s0 = qb * 64 + wid * 32;   // this wave's query base

    const size_t plane = (size_t)bh * kSz * kDH;
    const ushort* QhiP = Qhi + plane;
    const ushort* QloP = Qlo + plane;
    const ushort* KhiP = Khi + plane;
    const ushort* KloP = Klo + plane;
    const ushort* VthP = Vthi + plane;
    const ushort* VtlP = Vtlo + plane;
    const float scale = 0.08838834764831845f;  // 1/sqrt(128)

    // mask byte-stride detection (validated): uint8 bools vs int32
    const uint32_t w0 = *(const uint32_t*)mask;
    const int mstride = ((w0 & 0xFFu) != 0u && ((w0 >> 8) & 0xFFu) != 0u) ? 1 : 4;
    const uint8_t* mp8 = mask + (size_t)bb * kSz;
    const int*    mp32 = (const int*)mask + (size_t)bb * kSz;

    // ---- Q fragments to registers (direct global; validated layout) ----
    bf16x8 qh[8], ql[8];
    {
        const size_t qoff = (size_t)(s0 + l31) * kDH;
#pragma unroll
        for (int ks = 0; ks < 8; ++ks) {
            const int c = 2 * ks + half;
            qh[ks] = *(const bf16x8*)&QhiP[qoff + c * 8];
            ql[ks] = *(const bf16x8*)&QloP[qoff + c * 8];
        }
    }

    float mx   = -1e38f;
    float lsum = 0.0f;
    f32x16 oacc[4];
#pragma unroll
    for (int dt = 0; dt < 4; ++dt)
#pragma unroll
        for (int e = 0; e < 16; ++e) oacc[dt][e] = 0.0f;

    for (int kt = 0; kt < kSz / 32; ++kt) {
        const int j0 = kt * 32;

        // ---- QK^T: 2 accumulator chains for MFMA ILP ----
        f32x16 sa, sb;
#pragma unroll
        for (int r = 0; r < 16; ++r) { sa[r] = 0.0f; sb[r] = 0.0f; }
        {
            const size_t koff = (size_t)(j0 + l31) * kDH;
#pragma unroll
            for (int ks = 0; ks < 8; ++ks) {
                const int c = 2 * ks + half;
                const bf16x8 kh = *(const bf16x8*)&KhiP[koff + c * 8];
                const bf16x8 kl = *(const bf16x8*)&KloP[koff + c * 8];
                sa = __builtin_amdgcn_mfma_f32_32x32x16_bf16(kh, qh[ks], sa, 0, 0, 0);
                sb = __builtin_amdgcn_mfma_f32_32x32x16_bf16(kh, ql[ks], sb, 0, 0, 0);
                sb = __builtin_amdgcn_mfma_f32_32x32x16_bf16(kl, qh[ks], sb, 0, 0, 0);
            }
        }

        // ---- mask multipliers (post-exp masking; algebraically exact) ----
        float mmul[16];
#pragma unroll
        for (int g = 0; g < 4; ++g) {
            const int jm = j0 + 8 * g + 4 * half;
            if (mstride == 1) {
                const uchar4 m4 = *(const uchar4*)&mp8[jm];
                mmul[4 * g + 0] = m4.x ? 1.0f : 0.0f;
                mmul[4 * g + 1] = m4.y ? 1.0f : 0.0f;
                mmul[4 * g + 2] = m4.z ? 1.0f : 0.0f;
                mmul[4 * g + 3] = m4.w ? 1.0f : 0.0f;
            } else {
                const int4 m4 = *(const int4*)&mp32[jm];
                mmul[4 * g + 0] = m4.x ? 1.0f : 0.0f;
                mmul[4 * g + 1] = m4.y ? 1.0f : 0.0f;
                mmul[4 * g + 2] = m4.z ? 1.0f : 0.0f;
                mmul[4 * g + 3] = m4.w ? 1.0f : 0.0f;
            }
        }

        // ---- scores + in-register online softmax (defer-max, THR=8) ----
        float sv[16];
        float rmax = -1e38f;
#pragma unroll
        for (int r = 0; r < 16; ++r) {
            sv[r] = (sa[r] + sb[r]) * scale;
            rmax  = fmaxf(rmax, sv[r]);
        }
        rmax = fmaxf(rmax, __shfl_xor(rmax, 32));
        if (!__all(rmax <= mx + 8.0f)) {
            const float mnew  = fmaxf(mx, rmax);
            const float alpha = __expf(mx - mnew);
#pragma unroll
            for (int dt = 0; dt < 4; ++dt)
#pragma unroll
                for (int e = 0; e < 16; ++e) oacc[dt][e] *= alpha;
            lsum *= alpha;
            mx = mnew;
        }
        float pv[16];
        float rs = 0.0f;
#pragma unroll
        for (int r = 0; r < 16; ++r) {
            const float p = __expf(sv[r] - mx) * mmul[r];
            pv[r] = p;
            rs += p;
        }
        rs += __shfl_xor(rs, 32);
        lsum += rs;

        // ---- pack P to bf16 B-fragments in NATURAL register order ----
        union { uint u[8]; bf16x8 v[2]; } pb;
#pragma unroll
        for (int w = 0; w < 8; ++w)
            pb.u[w] = cvt_pk_bf16(pv[2 * w], pv[2 * w + 1]);

        // ---- PV: oacc[dt] += Vt(j-permuted) · P  (2-term split V) ----
#pragma unroll
        for (int dt = 0; dt < 4; ++dt) {
            const size_t vrow = (size_t)(dt * 32 + l31) * kSz + j0 + 4 * half;
#pragma unroll
            for (int ch = 0; ch < 2; ++ch) {
                const size_t a0 = vrow + ch * 16;
                const bf16x8 vh = ld2x8(&VthP[a0], &VthP[a0 + 8]);
                const bf16x8 vl = ld2x8(&VtlP[a0], &VtlP[a0 + 8]);
                oacc[dt] = __builtin_amdgcn_mfma_f32_32x32x16_bf16(vh, pb.v[ch], oacc[dt], 0, 0, 0);
                oacc[dt] = __builtin_amdgcn_mfma_f32_32x32x16_bf16(vl, pb.v[ch], oacc[dt], 0, 0, 0);
            }
        }
    }

    // ---- normalize + pack O as SPLIT bf16 B-fragments (reg order) ----
    const float linv = 1.0f / lsum;
    union { uint u[8][4]; bf16x8 v[8]; } ofh, ofl;
#pragma unroll
    for (int dc = 0; dc < 8; ++dc) {
        const int dt = dc >> 1;
        const int rb = (dc & 1) * 8;
#pragma unroll
        for (int w = 0; w < 4; ++w) {
            const float o0 = oacc[dt][rb + 2 * w]     * linv;
            const float o1 = oacc[dt][rb + 2 * w + 1] * linv;
            const uint u0 = __float_as_uint(o0);
            const uint u1 = __float_as_uint(o1);
            const uint hw = (u0 >> 16) | (u1 & 0xFFFF0000u);
            ofh.u[dc][w] = hw;
            ofl.u[dc][w] = cvt_pk_bf16(o0 - bf2f((ushort)(u0 >> 16)),
                                       o1 - bf2f((ushort)(u1 >> 16)));
        }
    }

    // ---- fused out-projection: y^T = Wo · O^T (Wo d-permuted loads) ----
    f32x16 ya[4];
#pragma unroll
    for (int et = 0; et < 4; ++et)
#pragma unroll
        for (int e = 0; e < 16; ++e) ya[et][e] = 0.0f;
#pragma unroll
    for (int et = 0; et < 4; ++et) {
        const size_t wrow = ((size_t)h * kDH + et * 32 + l31) * kDH + 4 * half;
#pragma unroll
        for (int dc = 0; dc < 8; ++dc) {
            const size_t a0 = wrow + dc * 16;
            const bf16x8 wh = ld2x8(&Wohi[a0], &Wohi[a0 + 8]);
            const bf16x8 wl = ld2x8(&Wolo[a0], &Wolo[a0 + 8]);
            ya[et] = __builtin_amdgcn_mfma_f32_32x32x16_bf16(wh, ofh.v[dc], ya[et], 0, 0, 0);
            ya[et] = __builtin_amdgcn_mfma_f32_32x32x16_bf16(wh, ofl.v[dc], ya[et], 0, 0, 0);
            ya[et] = __builtin_amdgcn_mfma_f32_32x32x16_bf16(wl, ofh.v[dc], ya[et], 0, 0, 0);
        }
    }

    // ---- bias + store: y^T col=i=l31, row e=(r&3)+8(r>>2)+4half ----
    {
        const int i = s0 + l31;
        float* orow = out + ((size_t)(bb * kSz + i)) * kDz + h * kDH;
#pragma unroll
        for (int et = 0; et < 4; ++et)
#pragma unroll
            for (int g = 0; g < 4; ++g) {
                const int e0 = et * 32 + 8 * g + 4 * half;
                const float4 bo4 = *(const float4*)&bo[h * kDH + e0];
                float4 y;
                y.x = ya[et][4 * g + 0] + bo4.x;
                y.y = ya[et][4 * g + 1] + bo4.y;
                y.z = ya[et][4 * g + 2] + bo4.z;
                y.w = ya[et][4 * g + 3] + bo4.w;
                *(float4*)&orow[e0] = y;
            }
    }
}

// ---------------------------------------------------------------------------
extern "C" void kernel_launch(void* const* d_in, const int* in_sizes, int n_in,
                              void* d_out, int out_size, void* d_ws, size_t ws_size,
                              hipStream_t stream)
{
    (void)in_sizes; (void)n_in; (void)out_size; (void)ws_size;
    const float*   x    = (const float*)d_in[0];
    const uint8_t* mask = (const uint8_t*)d_in[1];
    const float*   Wq   = (const float*)d_in[2];
    const float*   bq   = (const float*)d_in[3];
    const float*   Wk   = (const float*)d_in[4];
    const float*   bk   = (const float*)d_in[5];
    const float*   Wv   = (const float*)d_in[6];
    const float*   bv   = (const float*)d_in[7];
    const float*   Wo   = (const float*)d_in[8];
    const float*   bo   = (const float*)d_in[9];
    float* out = (float*)d_out;

    const size_t plane = (size_t)kBz * kHz * kSz * kDH;  // 8,388,608 elems
    ushort* Qhi  = (ushort*)d_ws;
    ushort* Qlo  = Qhi + plane;
    ushort* Khi  = Qlo + plane;
    ushort* Klo  = Khi + plane;
    ushort* Vthi = Klo + plane;
    ushort* Vtlo = Vthi + plane;
    ushort* Wohi = Vtlo + plane;
    ushort* Wolo = Wohi + (size_t)kHz * kDH * kDH;

    wo_split_kernel<<<dim3(kHz * kDH * kDH / 1024), 256, 0, stream>>>(Wo, Wohi, Wolo);
    qkv_proj_kernel<<<dim3(kDz / 128, kMz / 128, 3), 256, 0, stream>>>(
        x, Wq, Wk, Wv, bq, bk, bv, Qhi, Qlo, Khi, Klo, Vthi, Vtlo);
    attn_fused_kernel<<<dim3((kSz / 64) * kBz * kHz), 128, 0, stream>>>(
        Qhi, Qlo, Khi, Klo, Vthi, Vtlo, mask, Wohi, Wolo, bo, out);
}

// Round 7
// 710.520 us; speedup vs baseline: 1.7074x; 1.7074x over previous
//
#include <hip/hip_runtime.h>
#include <stdint.h>

// Problem constants (reference: B,S,D,H = 2,2048,2048,16; DH=128)
constexpr int kBz = 2;
constexpr int kSz = 2048;
constexpr int kDz = 2048;
constexpr int kHz = 16;
constexpr int kDH = 128;
constexpr int kMz = kBz * kSz;  // 4096 rows of x

typedef __attribute__((ext_vector_type(8)))  short bf16x8;
typedef __attribute__((ext_vector_type(16))) float f32x16;

__device__ __forceinline__ ushort f2bf_rne(float f) {
    const uint u = __float_as_uint(f);
    return (ushort)((u + 0x7FFFu + ((u >> 16) & 1u)) >> 16);
}
__device__ __forceinline__ ushort f2bf_hi(float f) {
    return (ushort)(__float_as_uint(f) >> 16);
}
__device__ __forceinline__ float bf2f(ushort h) {
    return __uint_as_float(((uint)h) << 16);
}
// pack 2 f32 -> 1 u32 of 2 RNE bf16 (low = a, high = b)
__device__ __forceinline__ uint cvt_pk_bf16(float a, float b) {
    uint r;
    asm("v_cvt_pk_bf16_f32 %0, %1, %2" : "=v"(r) : "v"(a), "v"(b));
    return r;
}
// split fp32 -> (hi = truncated bf16, lo = rne bf16 of residual); packed pairs
// slim version: trunc via and-mask pairs + cvt_pk for the residuals.
__device__ __forceinline__ void cvt_split(const float4 v, uint2& hi, uint2& lo) {
    const uint u0 = __float_as_uint(v.x), u1 = __float_as_uint(v.y);
    const uint u2 = __float_as_uint(v.z), u3 = __float_as_uint(v.w);
    hi.x = (u0 >> 16) | (u1 & 0xFFFF0000u);
    hi.y = (u2 >> 16) | (u3 & 0xFFFF0000u);
    lo.x = cvt_pk_bf16(v.x - __uint_as_float(u0 & 0xFFFF0000u),
                       v.y - __uint_as_float(u1 & 0xFFFF0000u));
    lo.y = cvt_pk_bf16(v.z - __uint_as_float(u2 & 0xFFFF0000u),
                       v.w - __uint_as_float(u3 & 0xFFFF0000u));
}

// ---------------------------------------------------------------------------
// Fragment-major workspace layouts (all per bh-plane of kSz*kDH ushorts):
//  Qf/Kf: [tile(32 rows)][ks 0..7][lane 0..63][elem 0..7]
//         value = M[row = tile*32 + (lane&31)][d = (2*ks + lane>>5)*8 + elem]
//  Vf:    [jtile][dt 0..3][ch 0..1][lane][elem]
//         value = V[j = jtile*32 + PERM(ch,lane>>5,elem)][d = dt*32 + (lane&31)]
//         PERM(ch,h,e) = 16*ch + 8*(e>>2) + 4*h + (e&3)   (matches P reg order)
//  Wof:   [h][et 0..3][dc 0..7][lane][elem]
//         value = Wo[h][row = et*32 + (lane&31)][d = dc*16 + 4*(lane>>5) + (e&3) + 8*(e>>2)]
// Every attn fragment load = one coalesced b128 (lane stride 16B).
// ---------------------------------------------------------------------------

// Kernel W: split Wo into fragment-major bf16 hi/lo planes.
__global__ __launch_bounds__(256)
void wo_split_kernel(const float* __restrict__ Wo,
                     ushort* __restrict__ Wofh, ushort* __restrict__ Wofl)
{
    const int h  = blockIdx.x >> 2;
    const int et = blockIdx.x & 3;
    const int t  = threadIdx.x;
    const int lane = t & 63;
    const int l31  = lane & 31;
    const int hf   = lane >> 5;
    const int row  = et * 32 + l31;
#pragma unroll
    for (int part = 0; part < 2; ++part) {
        const int dc = part * 4 + (t >> 6);
        const int dbase = dc * 16 + 4 * hf;
        const float4 wA = *(const float4*)&Wo[((size_t)(h * kDH + row)) * kDH + dbase];
        const float4 wB = *(const float4*)&Wo[((size_t)(h * kDH + row)) * kDH + dbase + 8];
        uint4 hv, lv;
        hv.x = (__float_as_uint(wA.x) >> 16) | (__float_as_uint(wA.y) & 0xFFFF0000u);
        hv.y = (__float_as_uint(wA.z) >> 16) | (__float_as_uint(wA.w) & 0xFFFF0000u);
        hv.z = (__float_as_uint(wB.x) >> 16) | (__float_as_uint(wB.y) & 0xFFFF0000u);
        hv.w = (__float_as_uint(wB.z) >> 16) | (__float_as_uint(wB.w) & 0xFFFF0000u);
        lv.x = cvt_pk_bf16(wA.x - __uint_as_float(__float_as_uint(wA.x) & 0xFFFF0000u),
                           wA.y - __uint_as_float(__float_as_uint(wA.y) & 0xFFFF0000u));
        lv.y = cvt_pk_bf16(wA.z - __uint_as_float(__float_as_uint(wA.z) & 0xFFFF0000u),
                           wA.w - __uint_as_float(__float_as_uint(wA.w) & 0xFFFF0000u));
        lv.z = cvt_pk_bf16(wB.x - __uint_as_float(__float_as_uint(wB.x) & 0xFFFF0000u),
                           wB.y - __uint_as_float(__float_as_uint(wB.y) & 0xFFFF0000u));
        lv.w = cvt_pk_bf16(wB.z - __uint_as_float(__float_as_uint(wB.z) & 0xFFFF0000u),
                           wB.w - __uint_as_float(__float_as_uint(wB.w) & 0xFFFF0000u));
        const size_t off = (size_t)(h * 4 + et) * 4096 + dc * 512 + lane * 8;
        *(uint4*)&Wofh[off] = hv;
        *(uint4*)&Wofl[off] = lv;
    }
}

// ---------------------------------------------------------------------------
// Kernel A: fused QKV projection via split-bf16 MFMA (validated R4-R6).
// Epilogue writes fragment-major layouts above.
// ---------------------------------------------------------------------------
__global__ __launch_bounds__(256)
void qkv_proj_kernel(const float* __restrict__ x,
                     const float* __restrict__ Wq, const float* __restrict__ Wk,
                     const float* __restrict__ Wv,
                     const float* __restrict__ bq, const float* __restrict__ bk,
                     const float* __restrict__ bv,
                     ushort* __restrict__ Qfh, ushort* __restrict__ Qfl,
                     ushort* __restrict__ Kfh, ushort* __restrict__ Kfl,
                     ushort* __restrict__ Vfh, ushort* __restrict__ Vfl)
{
    const int z = blockIdx.z;
    const float* W    = (z == 0) ? Wq : (z == 1) ? Wk : Wv;
    const float* bias = (z == 0) ? bq : (z == 1) ? bk : bv;

    __shared__ ushort AsHi[4 * 1032];
    __shared__ ushort AsLo[4 * 1032];
    __shared__ ushort BsHi[4 * 1032];
    __shared__ ushort BsLo[4 * 1032];

    const int tid  = threadIdx.x;
    const int lane = tid & 63;
    const int wid  = tid >> 6;
    const int wr   = (wid >> 1) * 64;
    const int wc   = (wid & 1) * 64;
    const int row0 = blockIdx.y * 128;
    const int col0 = blockIdx.x * 128;

    f32x16 acc[2][2];
#pragma unroll
    for (int fi = 0; fi < 2; ++fi)
#pragma unroll
        for (int fj = 0; fj < 2; ++fj)
#pragma unroll
            for (int e = 0; e < 16; ++e) acc[fi][fj][e] = 0.0f;

    for (int kt = 0; kt < kDz; kt += 32) {
#pragma unroll
        for (int t = 0; t < 4; ++t) {
            const int idx = tid + t * 256;
            const int m   = idx >> 3;
            const int q   = idx & 7;
            const int off = (q >> 1) * 1032 + m * 8 + (q & 1) * 4;
            {
                const float4 av = *(const float4*)&x[(size_t)(row0 + m) * kDz + kt + q * 4];
                uint2 ph, pl;
                cvt_split(av, ph, pl);
                *(uint2*)&AsHi[off] = ph;
                *(uint2*)&AsLo[off] = pl;
            }
            {
                const float4 wv4 = *(const float4*)&W[(size_t)(col0 + m) * kDz + kt + q * 4];
                uint2 ph, pl;
                cvt_split(wv4, ph, pl);
                *(uint2*)&BsHi[off] = ph;
                *(uint2*)&BsLo[off] = pl;
            }
        }
        __syncthreads();

#pragma unroll
        for (int ks = 0; ks < 2; ++ks) {
            const int base = (ks * 2 + (lane >> 5)) * 1032;
            bf16x8 ah[2], al[2], bh[2], bl[2];
#pragma unroll
            for (int f = 0; f < 2; ++f) {
                const int ma = (wr + f * 32 + (lane & 31)) * 8;
                ah[f] = *(const bf16x8*)&AsHi[base + ma];
                al[f] = *(const bf16x8*)&AsLo[base + ma];
                const int nb = (wc + f * 32 + (lane & 31)) * 8;
                bh[f] = *(const bf16x8*)&BsHi[base + nb];
                bl[f] = *(const bf16x8*)&BsLo[base + nb];
            }
#pragma unroll
            for (int fi = 0; fi < 2; ++fi)
#pragma unroll
                for (int fj = 0; fj < 2; ++fj) {
                    acc[fi][fj] = __builtin_amdgcn_mfma_f32_32x32x16_bf16(
                        ah[fi], bh[fj], acc[fi][fj], 0, 0, 0);
                    acc[fi][fj] = __builtin_amdgcn_mfma_f32_32x32x16_bf16(
                        ah[fi], bl[fj], acc[fi][fj], 0, 0, 0);
                    acc[fi][fj] = __builtin_amdgcn_mfma_f32_32x32x16_bf16(
                        al[fi], bh[fj], acc[fi][fj], 0, 0, 0);
                }
        }
        __syncthreads();
    }

    const int head = blockIdx.x;
    if (z < 2) {
        // Qf/Kf layout: [tile][ks][lane' = half*32 + i31][elem]
        ushort* HiP = (z == 0) ? Qfh : Kfh;
        ushort* LoP = (z == 0) ? Qfl : Kfl;
#pragma unroll
        for (int fj = 0; fj < 2; ++fj) {
            const int dh    = wc + fj * 32 + (lane & 31);
            const int ksq   = dh >> 4;
            const int halfq = (dh >> 3) & 1;
            const int eq    = dh & 7;
            const float bvs = bias[head * kDH + dh];
#pragma unroll
            for (int fi = 0; fi < 2; ++fi) {
                const int rbase = row0 + wr + fi * 32;
                const int bb    = rbase >> 11;
                const size_t tbase =
                    (size_t)(bb * kHz + head) * kSz * kDH +
                    (size_t)((rbase & (kSz - 1)) >> 5) * 4096 + ksq * 512 + eq;
#pragma unroll
                for (int g = 0; g < 4; ++g)
#pragma unroll
                    for (int e4 = 0; e4 < 4; ++e4) {
                        const int i31 = g * 8 + (lane >> 5) * 4 + e4;
                        const size_t idx = tbase + (size_t)(halfq * 32 + i31) * 8;
                        const float val = acc[fi][fj][g * 4 + e4] + bvs;
                        const ushort hb = f2bf_hi(val);
                        HiP[idx] = hb;
                        LoP[idx] = f2bf_rne(val - bf2f(hb));
                    }
            }
        }
    } else {
        // Vf layout: [jtile][dt][ch][lane][elem], PV j-permutation baked in.
#pragma unroll
        for (int fj = 0; fj < 2; ++fj) {
            const int dh   = wc + fj * 32 + (lane & 31);
            const int dt   = dh >> 5;
            const int l31v = dh & 31;
            const float bvs = bias[head * kDH + dh];
#pragma unroll
            for (int fi = 0; fi < 2; ++fi) {
                const int rbase = row0 + wr + fi * 32;
                const int bb    = rbase >> 11;
                const size_t tbase =
                    (size_t)(bb * kHz + head) * kSz * kDH +
                    (size_t)((rbase & (kSz - 1)) >> 5) * 4096 + dt * 1024;
#pragma unroll
                for (int g = 0; g < 4; ++g) {
                    const int ch  = (g >> 1) & 1;
                    const int epv = 4 * (g & 1);
                    const int hpv = lane >> 5;   // (jj>>2)&1
                    ushort4 h4, l4;
                    {
                        const float v0 = acc[fi][fj][g * 4 + 0] + bvs;
                        const float v1 = acc[fi][fj][g * 4 + 1] + bvs;
                        const float v2 = acc[fi][fj][g * 4 + 2] + bvs;
                        const float v3 = acc[fi][fj][g * 4 + 3] + bvs;
                        h4.x = f2bf_hi(v0); l4.x = f2bf_rne(v0 - bf2f(h4.x));
                        h4.y = f2bf_hi(v1); l4.y = f2bf_rne(v1 - bf2f(h4.y));
                        h4.z = f2bf_hi(v2); l4.z = f2bf_rne(v2 - bf2f(h4.z));
                        h4.w = f2bf_hi(v3); l4.w = f2bf_rne(v3 - bf2f(h4.w));
                    }
                    const size_t off =
                        tbase + ch * 512 + (size_t)(hpv * 32 + l31v) * 8 + epv;
                    *(ushort4*)&Vfh[off] = h4;
                    *(ushort4*)&Vfl[off] = l4;
                }
            }
        }
    }
}

// ---------------------------------------------------------------------------
// Kernel B: barrier-free all-MFMA flash attention + fused out-projection.
// 256 thr = 4 independent waves (shared bh + K/V tiles for L1 reuse); each
// wave owns 32 queries, iterates all 64 KV tiles.  NO LDS, NO barriers.
// ALL loads are coalesced b128 from the fragment-major layouts.
// Math identical to round 6 (validated): swapped QK^T, in-register online
// softmax with defer-max THR=8, multiplicative mask, P/O in register order.
// ---------------------------------------------------------------------------
__global__ __launch_bounds__(256, 2)
void attn_fused_kernel(const ushort* __restrict__ Qfh, const ushort* __restrict__ Qfl,
                       const ushort* __restrict__ Kfh, const ushort* __restrict__ Kfl,
                       const ushort* __restrict__ Vfh, const ushort* __restrict__ Vfl,
                       const uint8_t* __restrict__ mask,
                       const ushort* __restrict__ Wofh, const ushort* __restrict__ Wofl,
                       const float* __restrict__ bo, float* __restrict__ out)
{
    const int tid  = threadIdx.x;
    const int lane = tid & 63;
    const int wid  = tid >> 6;       // 0..3: which 32-query group
    const int half = lane >> 5;
    const int l31  = lane & 31;

    // XCD-aware swizzle: 512 blocks = 8 XCDs x 64
    const int nb = (blockIdx.x & 7) * 64 + (blockIdx.x >> 3);
    const int bh = nb >> 4;          // 32 bh
    const int qb = nb & 15;          // 16 q-blocks of 128
    const int bb = bh >> 4;
    const int h  = bh & 15;
    const int s0 = qb * 128 + wid * 32;

    const size_t plane = (size_t)bh * kSz * kDH;
    const float scale = 0.08838834764831845f;  // 1/sqrt(128)

    // mask byte-stride detection (validated): uint8 bools vs int32
    const uint32_t w0 = *(const uint32_t*)mask;
    const int mstride = ((w0 & 0xFFu) != 0u && ((w0 >> 8) & 0xFFu) != 0u) ? 1 : 4;
    const uint8_t* mp8 = mask + (size_t)bb * kSz;
    const int*    mp32 = (const int*)mask + (size_t)bb * kSz;

    // ---- Q fragments (8 coalesced b128 per plane) ----
    bf16x8 qh[8], ql[8];
    {
        const size_t qbase = plane + (size_t)(s0 >> 5) * 4096 + lane * 8;
#pragma unroll
        for (int ks = 0; ks < 8; ++ks) {
            qh[ks] = *(const bf16x8*)&Qfh[qbase + ks * 512];
            ql[ks] = *(const bf16x8*)&Qfl[qbase + ks * 512];
        }
    }

    float mx   = -1e38f;
    float lsum = 0.0f;
    f32x16 oacc[4];
#pragma unroll
    for (int dt = 0; dt < 4; ++dt)
#pragma unroll
        for (int e = 0; e < 16; ++e) oacc[dt][e] = 0.0f;

    for (int kt = 0; kt < kSz / 32; ++kt) {
        const int j0 = kt * 32;
        const size_t tb = plane + (size_t)kt * 4096 + lane * 8;

        // ---- QK^T: 2 accumulator chains, A=K coalesced b128 frags ----
        f32x16 sa, sb;
#pragma unroll
        for (int r = 0; r < 16; ++r) { sa[r] = 0.0f; sb[r] = 0.0f; }
#pragma unroll
        for (int ks = 0; ks < 8; ++ks) {
            const bf16x8 kh = *(const bf16x8*)&Kfh[tb + ks * 512];
            const bf16x8 kl = *(const bf16x8*)&Kfl[tb + ks * 512];
            sa = __builtin_amdgcn_mfma_f32_32x32x16_bf16(kh, qh[ks], sa, 0, 0, 0);
            sb = __builtin_amdgcn_mfma_f32_32x32x16_bf16(kh, ql[ks], sb, 0, 0, 0);
            sb = __builtin_amdgcn_mfma_f32_32x32x16_bf16(kl, qh[ks], sb, 0, 0, 0);
        }

        // ---- mask multipliers (post-exp masking; algebraically exact) ----
        float mmul[16];
#pragma unroll
        for (int g = 0; g < 4; ++g) {
            const int jm = j0 + 8 * g + 4 * half;
            if (mstride == 1) {
                const uchar4 m4 = *(const uchar4*)&mp8[jm];
                mmul[4 * g + 0] = m4.x ? 1.0f : 0.0f;
                mmul[4 * g + 1] = m4.y ? 1.0f : 0.0f;
                mmul[4 * g + 2] = m4.z ? 1.0f : 0.0f;
                mmul[4 * g + 3] = m4.w ? 1.0f : 0.0f;
            } else {
                const int4 m4 = *(const int4*)&mp32[jm];
                mmul[4 * g + 0] = m4.x ? 1.0f : 0.0f;
                mmul[4 * g + 1] = m4.y ? 1.0f : 0.0f;
                mmul[4 * g + 2] = m4.z ? 1.0f : 0.0f;
                mmul[4 * g + 3] = m4.w ? 1.0f : 0.0f;
            }
        }

        // ---- scores + in-register online softmax (defer-max, THR=8) ----
        float sv[16];
        float rmax = -1e38f;
#pragma unroll
        for (int r = 0; r < 16; ++r) {
            sv[r] = (sa[r] + sb[r]) * scale;
            rmax  = fmaxf(rmax, sv[r]);
        }
        rmax = fmaxf(rmax, __shfl_xor(rmax, 32));
        if (!__all(rmax <= mx + 8.0f)) {
            const float mnew  = fmaxf(mx, rmax);
            const float alpha = __expf(mx - mnew);
#pragma unroll
            for (int dt = 0; dt < 4; ++dt)
#pragma unroll
                for (int e = 0; e < 16; ++e) oacc[dt][e] *= alpha;
            lsum *= alpha;
            mx = mnew;
        }
        float pv[16];
        float rs = 0.0f;
#pragma unroll
        for (int r = 0; r < 16; ++r) {
            const float p = __expf(sv[r] - mx) * mmul[r];
            pv[r] = p;
            rs += p;
        }
        rs += __shfl_xor(rs, 32);
        lsum += rs;

        // ---- pack P to bf16 B-fragments in natural register order ----
        union { uint u[8]; bf16x8 v[2]; } pb;
#pragma unroll
        for (int w = 0; w < 8; ++w)
            pb.u[w] = cvt_pk_bf16(pv[2 * w], pv[2 * w + 1]);

        // ---- PV: A=Vf coalesced b128 frags (j-perm baked into layout) ----
#pragma unroll
        for (int dt = 0; dt < 4; ++dt) {
            const size_t vb = tb + dt * 1024;
#pragma unroll
            for (int ch = 0; ch < 2; ++ch) {
                const bf16x8 vh = *(const bf16x8*)&Vfh[vb + ch * 512];
                const bf16x8 vl = *(const bf16x8*)&Vfl[vb + ch * 512];
                oacc[dt] = __builtin_amdgcn_mfma_f32_32x32x16_bf16(vh, pb.v[ch], oacc[dt], 0, 0, 0);
                oacc[dt] = __builtin_amdgcn_mfma_f32_32x32x16_bf16(vl, pb.v[ch], oacc[dt], 0, 0, 0);
            }
        }
    }

    // ---- normalize + pack O as split bf16 B-fragments (reg order) ----
    const float linv = 1.0f / lsum;
    union { uint u[8][4]; bf16x8 v[8]; } ofh, ofl;
#pragma unroll
    for (int dc = 0; dc < 8; ++dc) {
        const int dt = dc >> 1;
        const int rb = (dc & 1) * 8;
#pragma unroll
        for (int w = 0; w < 4; ++w) {
            const float o0 = oacc[dt][rb + 2 * w]     * linv;
            const float o1 = oacc[dt][rb + 2 * w + 1] * linv;
            const uint u0 = __float_as_uint(o0);
            const uint u1 = __float_as_uint(o1);
            ofh.u[dc][w] = (u0 >> 16) | (u1 & 0xFFFF0000u);
            ofl.u[dc][w] = cvt_pk_bf16(o0 - __uint_as_float(u0 & 0xFFFF0000u),
                                       o1 - __uint_as_float(u1 & 0xFFFF0000u));
        }
    }

    // ---- fused out-projection: A=Wof coalesced b128 frags ----
    f32x16 ya[4];
#pragma unroll
    for (int et = 0; et < 4; ++et)
#pragma unroll
        for (int e = 0; e < 16; ++e) ya[et][e] = 0.0f;
#pragma unroll
    for (int et = 0; et < 4; ++et) {
        const size_t wb = (size_t)(h * 4 + et) * 4096 + lane * 8;
#pragma unroll
        for (int dc = 0; dc < 8; ++dc) {
            const bf16x8 wh = *(const bf16x8*)&Wofh[wb + dc * 512];
            const bf16x8 wl = *(const bf16x8*)&Wofl[wb + dc * 512];
            ya[et] = __builtin_amdgcn_mfma_f32_32x32x16_bf16(wh, ofh.v[dc], ya[et], 0, 0, 0);
            ya[et] = __builtin_amdgcn_mfma_f32_32x32x16_bf16(wh, ofl.v[dc], ya[et], 0, 0, 0);
            ya[et] = __builtin_amdgcn_mfma_f32_32x32x16_bf16(wl, ofh.v[dc], ya[et], 0, 0, 0);
        }
    }

    // ---- bias + store (validated): y^T col=i=l31, row e=(r&3)+8(r>>2)+4half ----
    {
        const int i = s0 + l31;
        float* orow = out + ((size_t)(bb * kSz + i)) * kDz + h * kDH;
#pragma unroll
        for (int et = 0; et < 4; ++et)
#pragma unroll
            for (int g = 0; g < 4; ++g) {
                const int e0 = et * 32 + 8 * g + 4 * half;
                const float4 bo4 = *(const float4*)&bo[h * kDH + e0];
                float4 y;
                y.x = ya[et][4 * g + 0] + bo4.x;
                y.y = ya[et][4 * g + 1] + bo4.y;
                y.z = ya[et][4 * g + 2] + bo4.z;
                y.w = ya[et][4 * g + 3] + bo4.w;
                *(float4*)&orow[e0] = y;
            }
    }
}

// ---------------------------------------------------------------------------
extern "C" void kernel_launch(void* const* d_in, const int* in_sizes, int n_in,
                              void* d_out, int out_size, void* d_ws, size_t ws_size,
                              hipStream_t stream)
{
    (void)in_sizes; (void)n_in; (void)out_size; (void)ws_size;
    const float*   x    = (const float*)d_in[0];
    const uint8_t* mask = (const uint8_t*)d_in[1];
    const float*   Wq   = (const float*)d_in[2];
    const float*   bq   = (const float*)d_in[3];
    const float*   Wk   = (const float*)d_in[4];
    const float*   bk   = (const float*)d_in[5];
    const float*   Wv   = (const float*)d_in[6];
    const float*   bv   = (const float*)d_in[7];
    const float*   Wo   = (const float*)d_in[8];
    const float*   bo   = (const float*)d_in[9];
    float* out = (float*)d_out;

    const size_t plane = (size_t)kBz * kHz * kSz * kDH;  // 8,388,608 elems
    ushort* Qfh = (ushort*)d_ws;
    ushort* Qfl = Qfh + plane;
    ushort* Kfh = Qfl + plane;
    ushort* Kfl = Kfh + plane;
    ushort* Vfh = Kfl + plane;
    ushort* Vfl = Vfh + plane;
    ushort* Wofh = Vfl + plane;
    ushort* Wofl = Wofh + (size_t)kHz * kDH * kDH;

    wo_split_kernel<<<dim3(kHz * 4), 256, 0, stream>>>(Wo, Wofh, Wofl);
    qkv_proj_kernel<<<dim3(kDz / 128, kMz / 128, 3), 256, 0, stream>>>(
        x, Wq, Wk, Wv, bq, bk, bv, Qfh, Qfl, Kfh, Kfl, Vfh, Vfl);
    attn_fused_kernel<<<dim3((kSz / 128) * kBz * kHz), 256, 0, stream>>>(
        Qfh, Qfl, Kfh, Kfl, Vfh, Vfl, mask, Wofh, Wofl, bo, out);
}

// Round 10
// 564.243 us; speedup vs baseline: 2.1500x; 1.2592x over previous
//
#include <hip/hip_runtime.h>
#include <stdint.h>

// Problem constants (reference: B,S,D,H = 2,2048,2048,16; DH=128)
constexpr int kBz = 2;
constexpr int kSz = 2048;
constexpr int kDz = 2048;
constexpr int kHz = 16;
constexpr int kDH = 128;
constexpr int kMz = kBz * kSz;  // 4096 rows of x

typedef __attribute__((ext_vector_type(8)))  short bf16x8;
typedef __attribute__((ext_vector_type(16))) float f32x16;

__device__ __forceinline__ ushort f2bf_rne(float f) {
    const uint u = __float_as_uint(f);
    return (ushort)((u + 0x7FFFu + ((u >> 16) & 1u)) >> 16);
}
// pack 2 f32 -> 1 u32 of 2 RNE bf16 (low = a, high = b)
__device__ __forceinline__ uint cvt_pk_bf16(float a, float b) {
    uint r;
    asm("v_cvt_pk_bf16_f32 %0, %1, %2" : "=v"(r) : "v"(a), "v"(b));
    return r;
}

// ---------------------------------------------------------------------------
// Fragment-major workspace layouts (validated round 7), SINGLE bf16 plane:
//  Qf/Kf: [tile(32 rows)][ks 0..7][lane 0..63][elem 0..7]
//         value = M[row = tile*32 + (lane&31)][d = (2*ks + lane>>5)*8 + elem]
//  Vf:    [jtile][dt 0..3][ch 0..1][lane][elem]
//         value = V[j = jtile*32 + PERM(ch,lane>>5,elem)][d = dt*32 + (lane&31)]
//         PERM(ch,h,e) = 16*ch + 8*(e>>2) + 4*h + (e&3)   (matches P reg order)
//  Wof:   [h][et 0..3][dc 0..7][lane][elem]
//         value = Wo[h][row = et*32 + (lane&31)][d = dc*16 + 4*(lane>>5) + (e&3) + 8*(e>>2)]
// Every attn fragment load = one coalesced b128 (lane stride 16B).
// ---------------------------------------------------------------------------

// Kernel W: Wo -> fragment-major RNE-bf16 plane.
__global__ __launch_bounds__(256)
void wo_split_kernel(const float* __restrict__ Wo, ushort* __restrict__ Wof)
{
    const int h  = blockIdx.x >> 2;
    const int et = blockIdx.x & 3;
    const int t  = threadIdx.x;
    const int lane = t & 63;
    const int l31  = lane & 31;
    const int hf   = lane >> 5;
    const int row  = et * 32 + l31;
#pragma unroll
    for (int part = 0; part < 2; ++part) {
        const int dc = part * 4 + (t >> 6);
        const int dbase = dc * 16 + 4 * hf;
        const float4 wA = *(const float4*)&Wo[((size_t)(h * kDH + row)) * kDH + dbase];
        const float4 wB = *(const float4*)&Wo[((size_t)(h * kDH + row)) * kDH + dbase + 8];
        uint4 hv;
        hv.x = cvt_pk_bf16(wA.x, wA.y);
        hv.y = cvt_pk_bf16(wA.z, wA.w);
        hv.z = cvt_pk_bf16(wB.x, wB.y);
        hv.w = cvt_pk_bf16(wB.z, wB.w);
        const size_t off = (size_t)(h * 4 + et) * 4096 + dc * 512 + lane * 8;
        *(uint4*)&Wof[off] = hv;
    }
}

// ---------------------------------------------------------------------------
// Kernel A: fused QKV projection, plain bf16 MFMA (structure = validated R7,
// with the lo-plane work deleted).  Staging packs fp32 -> RNE bf16 via
// cvt_pk; LDS halves to 16.5 KB; 4 MFMA per 16-k step.
// ---------------------------------------------------------------------------
__global__ __launch_bounds__(256)
void qkv_proj_kernel(const float* __restrict__ x,
                     const float* __restrict__ Wq, const float* __restrict__ Wk,
                     const float* __restrict__ Wv,
                     const float* __restrict__ bq, const float* __restrict__ bk,
                     const float* __restrict__ bv,
                     ushort* __restrict__ Qf, ushort* __restrict__ Kf,
                     ushort* __restrict__ Vf)
{
    const int z = blockIdx.z;
    const float* W    = (z == 0) ? Wq : (z == 1) ? Wk : Wv;
    const float* bias = (z == 0) ? bq : (z == 1) ? bk : bv;

    // plane stride 1032 ushorts = 2064 B (16B-aligned, breaks bank period)
    __shared__ ushort As[4 * 1032];
    __shared__ ushort Bs[4 * 1032];

    const int tid  = threadIdx.x;
    const int lane = tid & 63;
    const int wid  = tid >> 6;
    const int wr   = (wid >> 1) * 64;
    const int wc   = (wid & 1) * 64;
    const int row0 = blockIdx.y * 128;
    const int col0 = blockIdx.x * 128;

    f32x16 acc[2][2];
#pragma unroll
    for (int fi = 0; fi < 2; ++fi)
#pragma unroll
        for (int fj = 0; fj < 2; ++fj)
#pragma unroll
            for (int e = 0; e < 16; ++e) acc[fi][fj][e] = 0.0f;

    for (int kt = 0; kt < kDz; kt += 32) {
#pragma unroll
        for (int t = 0; t < 4; ++t) {
            const int idx = tid + t * 256;   // 0..1023
            const int m   = idx >> 3;        // row 0..127
            const int q   = idx & 7;         // float4 index along k
            const int off = (q >> 1) * 1032 + m * 8 + (q & 1) * 4;  // ushort idx
            {
                const float4 av = *(const float4*)&x[(size_t)(row0 + m) * kDz + kt + q * 4];
                uint2 p;
                p.x = cvt_pk_bf16(av.x, av.y);
                p.y = cvt_pk_bf16(av.z, av.w);
                *(uint2*)&As[off] = p;
            }
            {
                const float4 wv4 = *(const float4*)&W[(size_t)(col0 + m) * kDz + kt + q * 4];
                uint2 p;
                p.x = cvt_pk_bf16(wv4.x, wv4.y);
                p.y = cvt_pk_bf16(wv4.z, wv4.w);
                *(uint2*)&Bs[off] = p;
            }
        }
        __syncthreads();

#pragma unroll
        for (int ks = 0; ks < 2; ++ks) {
            const int base = (ks * 2 + (lane >> 5)) * 1032;
            bf16x8 ah[2], bh[2];
#pragma unroll
            for (int f = 0; f < 2; ++f) {
                ah[f] = *(const bf16x8*)&As[base + (wr + f * 32 + (lane & 31)) * 8];
                bh[f] = *(const bf16x8*)&Bs[base + (wc + f * 32 + (lane & 31)) * 8];
            }
#pragma unroll
            for (int fi = 0; fi < 2; ++fi)
#pragma unroll
                for (int fj = 0; fj < 2; ++fj)
                    acc[fi][fj] = __builtin_amdgcn_mfma_f32_32x32x16_bf16(
                        ah[fi], bh[fj], acc[fi][fj], 0, 0, 0);
        }
        __syncthreads();
    }

    // ---- epilogue (validated R7 layouts, single plane, RNE) ----
    const int head = blockIdx.x;
    if (z < 2) {
        ushort* P = (z == 0) ? Qf : Kf;
#pragma unroll
        for (int fj = 0; fj < 2; ++fj) {
            const int dh    = wc + fj * 32 + (lane & 31);
            const int ksq   = dh >> 4;
            const int halfq = (dh >> 3) & 1;
            const int eq    = dh & 7;
            const float bvs = bias[head * kDH + dh];
#pragma unroll
            for (int fi = 0; fi < 2; ++fi) {
                const int rbase = row0 + wr + fi * 32;
                const int bb    = rbase >> 11;
                const size_t tbase =
                    (size_t)(bb * kHz + head) * kSz * kDH +
                    (size_t)((rbase & (kSz - 1)) >> 5) * 4096 + ksq * 512 + eq;
#pragma unroll
                for (int g = 0; g < 4; ++g)
#pragma unroll
                    for (int e4 = 0; e4 < 4; ++e4) {
                        const int i31 = g * 8 + (lane >> 5) * 4 + e4;
                        const size_t idx = tbase + (size_t)(halfq * 32 + i31) * 8;
                        P[idx] = f2bf_rne(acc[fi][fj][g * 4 + e4] + bvs);
                    }
            }
        }
    } else {
        // Vf: [jtile][dt][ch][lane][elem] with PV j-permutation baked in.
#pragma unroll
        for (int fj = 0; fj < 2; ++fj) {
            const int dh   = wc + fj * 32 + (lane & 31);
            const int dt   = dh >> 5;
            const int l31v = dh & 31;
            const float bvs = bias[head * kDH + dh];
#pragma unroll
            for (int fi = 0; fi < 2; ++fi) {
                const int rbase = row0 + wr + fi * 32;
                const int bb    = rbase >> 11;
                const size_t tbase =
                    (size_t)(bb * kHz + head) * kSz * kDH +
                    (size_t)((rbase & (kSz - 1)) >> 5) * 4096 + dt * 1024;
#pragma unroll
                for (int g = 0; g < 4; ++g) {
                    const int ch  = (g >> 1) & 1;
                    const int epv = 4 * (g & 1);
                    const int hpv = lane >> 5;
                    ushort4 h4;
                    h4.x = f2bf_rne(acc[fi][fj][g * 4 + 0] + bvs);
                    h4.y = f2bf_rne(acc[fi][fj][g * 4 + 1] + bvs);
                    h4.z = f2bf_rne(acc[fi][fj][g * 4 + 2] + bvs);
                    h4.w = f2bf_rne(acc[fi][fj][g * 4 + 3] + bvs);
                    const size_t off =
                        tbase + ch * 512 + (size_t)(hpv * 32 + l31v) * 8 + epv;
                    *(ushort4*)&Vf[off] = h4;
                }
            }
        }
    }
}

// ---------------------------------------------------------------------------
// Kernel B: barrier-free all-MFMA flash attention + fused out-projection.
// Structure byte-identical to validated round 7, with the lo-plane terms
// deleted (1-term bf16).  4 independent waves, no LDS, no barriers, all
// loads coalesced b128 from fragment-major layouts.
// ---------------------------------------------------------------------------
__global__ __launch_bounds__(256, 2)
void attn_fused_kernel(const ushort* __restrict__ Qf, const ushort* __restrict__ Kf,
                       const ushort* __restrict__ Vf,
                       const uint8_t* __restrict__ mask,
                       const ushort* __restrict__ Wof,
                       const float* __restrict__ bo, float* __restrict__ out)
{
    const int tid  = threadIdx.x;
    const int lane = tid & 63;
    const int wid  = tid >> 6;       // 0..3: which 32-query group
    const int half = lane >> 5;
    const int l31  = lane & 31;

    // XCD-aware swizzle (validated): 512 blocks = 8 XCDs x 64
    const int nb = (blockIdx.x & 7) * 64 + (blockIdx.x >> 3);
    const int bh = nb >> 4;
    const int qb = nb & 15;
    const int bb = bh >> 4;
    const int h  = bh & 15;
    const int s0 = qb * 128 + wid * 32;

    const size_t plane = (size_t)bh * kSz * kDH;
    const float scale = 0.08838834764831845f;  // 1/sqrt(128)

    // mask byte-stride detection (validated): uint8 bools vs int32
    const uint32_t w0 = *(const uint32_t*)mask;
    const int mstride = ((w0 & 0xFFu) != 0u && ((w0 >> 8) & 0xFFu) != 0u) ? 1 : 4;
    const uint8_t* mp8 = mask + (size_t)bb * kSz;
    const int*    mp32 = (const int*)mask + (size_t)bb * kSz;

    // ---- Q fragments (8 coalesced b128) ----
    bf16x8 qh[8];
    {
        const size_t qbase = plane + (size_t)(s0 >> 5) * 4096 + lane * 8;
#pragma unroll
        for (int ks = 0; ks < 8; ++ks)
            qh[ks] = *(const bf16x8*)&Qf[qbase + ks * 512];
    }

    float mx   = -1e38f;
    float lsum = 0.0f;
    f32x16 oacc[4];
#pragma unroll
    for (int dt = 0; dt < 4; ++dt)
#pragma unroll
        for (int e = 0; e < 16; ++e) oacc[dt][e] = 0.0f;

    for (int kt = 0; kt < kSz / 32; ++kt) {
        const int j0 = kt * 32;
        const size_t tb = plane + (size_t)kt * 4096 + lane * 8;

        // ---- QK^T: A=K coalesced b128 frags ----
        f32x16 sa;
#pragma unroll
        for (int r = 0; r < 16; ++r) sa[r] = 0.0f;
#pragma unroll
        for (int ks = 0; ks < 8; ++ks) {
            const bf16x8 kh = *(const bf16x8*)&Kf[tb + ks * 512];
            sa = __builtin_amdgcn_mfma_f32_32x32x16_bf16(kh, qh[ks], sa, 0, 0, 0);
        }

        // ---- mask multipliers (post-exp masking; algebraically exact) ----
        float mmul[16];
#pragma unroll
        for (int g = 0; g < 4; ++g) {
            const int jm = j0 + 8 * g + 4 * half;
            if (mstride == 1) {
                const uchar4 m4 = *(const uchar4*)&mp8[jm];
                mmul[4 * g + 0] = m4.x ? 1.0f : 0.0f;
                mmul[4 * g + 1] = m4.y ? 1.0f : 0.0f;
                mmul[4 * g + 2] = m4.z ? 1.0f : 0.0f;
                mmul[4 * g + 3] = m4.w ? 1.0f : 0.0f;
            } else {
                const int4 m4 = *(const int4*)&mp32[jm];
                mmul[4 * g + 0] = m4.x ? 1.0f : 0.0f;
                mmul[4 * g + 1] = m4.y ? 1.0f : 0.0f;
                mmul[4 * g + 2] = m4.z ? 1.0f : 0.0f;
                mmul[4 * g + 3] = m4.w ? 1.0f : 0.0f;
            }
        }

        // ---- scores + in-register online softmax (defer-max, THR=8) ----
        float sv[16];
        float rmax = -1e38f;
#pragma unroll
        for (int r = 0; r < 16; ++r) {
            sv[r] = sa[r] * scale;
            rmax  = fmaxf(rmax, sv[r]);
        }
        rmax = fmaxf(rmax, __shfl_xor(rmax, 32));
        if (!__all(rmax <= mx + 8.0f)) {
            const float mnew  = fmaxf(mx, rmax);
            const float alpha = __expf(mx - mnew);
#pragma unroll
            for (int dt = 0; dt < 4; ++dt)
#pragma unroll
                for (int e = 0; e < 16; ++e) oacc[dt][e] *= alpha;
            lsum *= alpha;
            mx = mnew;
        }
        float pv[16];
        float rs = 0.0f;
#pragma unroll
        for (int r = 0; r < 16; ++r) {
            const float p = __expf(sv[r] - mx) * mmul[r];
            pv[r] = p;
            rs += p;
        }
        rs += __shfl_xor(rs, 32);
        lsum += rs;

        // ---- pack P to bf16 B-fragments in natural register order ----
        union { uint u[8]; bf16x8 v[2]; } pb;
#pragma unroll
        for (int w = 0; w < 8; ++w)
            pb.u[w] = cvt_pk_bf16(pv[2 * w], pv[2 * w + 1]);

        // ---- PV: A=Vf coalesced b128 frags (j-perm baked into layout) ----
#pragma unroll
        for (int dt = 0; dt < 4; ++dt) {
            const size_t vb = tb + dt * 1024;
#pragma unroll
            for (int ch = 0; ch < 2; ++ch) {
                const bf16x8 vh = *(const bf16x8*)&Vf[vb + ch * 512];
                oacc[dt] = __builtin_amdgcn_mfma_f32_32x32x16_bf16(vh, pb.v[ch], oacc[dt], 0, 0, 0);
            }
        }
    }

    // ---- normalize + pack O as bf16 B-fragments (reg order) ----
    const float linv = 1.0f / lsum;
    union { uint u[8][4]; bf16x8 v[8]; } of;
#pragma unroll
    for (int dc = 0; dc < 8; ++dc) {
        const int dt = dc >> 1;
        const int rb = (dc & 1) * 8;
#pragma unroll
        for (int w = 0; w < 4; ++w)
            of.u[dc][w] = cvt_pk_bf16(oacc[dt][rb + 2 * w] * linv,
                                      oacc[dt][rb + 2 * w + 1] * linv);
    }

    // ---- fused out-projection: A=Wof coalesced b128 frags ----
    f32x16 ya[4];
#pragma unroll
    for (int et = 0; et < 4; ++et)
#pragma unroll
        for (int e = 0; e < 16; ++e) ya[et][e] = 0.0f;
#pragma unroll
    for (int et = 0; et < 4; ++et) {
        const size_t wb = (size_t)(h * 4 + et) * 4096 + lane * 8;
#pragma unroll
        for (int dc = 0; dc < 8; ++dc) {
            const bf16x8 wh = *(const bf16x8*)&Wof[wb + dc * 512];
            ya[et] = __builtin_amdgcn_mfma_f32_32x32x16_bf16(wh, of.v[dc], ya[et], 0, 0, 0);
        }
    }

    // ---- bias + store (validated): y^T col=i=l31, row e=(r&3)+8(r>>2)+4half ----
    {
        const int i = s0 + l31;
        float* orow = out + ((size_t)(bb * kSz + i)) * kDz + h * kDH;
#pragma unroll
        for (int et = 0; et < 4; ++et)
#pragma unroll
            for (int g = 0; g < 4; ++g) {
                const int e0 = et * 32 + 8 * g + 4 * half;
                const float4 bo4 = *(const float4*)&bo[h * kDH + e0];
                float4 y;
                y.x = ya[et][4 * g + 0] + bo4.x;
                y.y = ya[et][4 * g + 1] + bo4.y;
                y.z = ya[et][4 * g + 2] + bo4.z;
                y.w = ya[et][4 * g + 3] + bo4.w;
                *(float4*)&orow[e0] = y;
            }
    }
}

// ---------------------------------------------------------------------------
extern "C" void kernel_launch(void* const* d_in, const int* in_sizes, int n_in,
                              void* d_out, int out_size, void* d_ws, size_t ws_size,
                              hipStream_t stream)
{
    (void)in_sizes; (void)n_in; (void)out_size; (void)ws_size;
    const float*   x    = (const float*)d_in[0];
    const uint8_t* mask = (const uint8_t*)d_in[1];
    const float*   Wq   = (const float*)d_in[2];
    const float*   bq   = (const float*)d_in[3];
    const float*   Wk   = (const float*)d_in[4];
    const float*   bk   = (const float*)d_in[5];
    const float*   Wv   = (const float*)d_in[6];
    const float*   bv   = (const float*)d_in[7];
    const float*   Wo   = (const float*)d_in[8];
    const float*   bo   = (const float*)d_in[9];
    float* out = (float*)d_out;

    // workspace: Qf,Kf,Vf fragment-major bf16 planes + Wof = 50.9 MB
    const size_t plane = (size_t)kBz * kHz * kSz * kDH;  // 8,388,608 elems
    ushort* Qf  = (ushort*)d_ws;
    ushort* Kf  = Qf + plane;
    ushort* Vf  = Kf + plane;
    ushort* Wof = Vf + plane;

    wo_split_kernel<<<dim3(kHz * 4), 256, 0, stream>>>(Wo, Wof);
    qkv_proj_kernel<<<dim3(kDz / 128, kMz / 128, 3), 256, 0, stream>>>(
        x, Wq, Wk, Wv, bq, bk, bv, Qf, Kf, Vf);
    attn_fused_kernel<<<dim3((kSz / 128) * kBz * kHz), 256, 0, stream>>>(
        Qf, Kf, Vf, mask, Wof, bo, out);
}